// Round 1
// baseline (131.209 us; speedup 1.0000x reference)
//
#include <hip/hip_runtime.h>

// YOLO decode: B=32 images, 3 anchors, 85 fields (need first 5), H=W in {13,26,52}.
// One (cell, anchor) pair per thread: output row index == global pair index,
// so LDS staging + contiguous float4 flush is exact and simple.
constexpr int B_IMG = 32;
constexpr int R13 = B_IMG * 13 * 13 * 3;   // 16224 rows
constexpr int R26 = B_IMG * 26 * 26 * 3;   // 64896 rows
constexpr int R52 = B_IMG * 52 * 52 * 3;   // 259584 rows

constexpr int ROWS_PER_BLK = 256;
constexpr int BLK13 = (R13 + ROWS_PER_BLK - 1) / ROWS_PER_BLK;  // 64  (tail 96 rows)
constexpr int BLK26 = (R26 + ROWS_PER_BLK - 1) / ROWS_PER_BLK;  // 254 (tail 128 rows)
constexpr int BLK52 = (R52 + ROWS_PER_BLK - 1) / ROWS_PER_BLK;  // 1014 (exact)
constexpr int NBLK  = BLK13 + BLK26 + BLK52;                    // 1332 blocks ~ 5.2/CU

template <int H>
__device__ __forceinline__ void decode_head_rows(
    const float* __restrict__ in,   // head input base (B,255,H,W)
    float* __restrict__ outf,       // head output base (floats)
    int blk, int tid, float thresh,
    float aw0, float ah0, float aw1, float ah1, float aw2, float ah2) {
    constexpr int W = H;
    constexpr int PLANE = H * W;
    constexpr int NROWS = B_IMG * PLANE * 3;
    constexpr float t = 416.0f / (float)H;

    __shared__ float lds[ROWS_PER_BLK * 5];  // 5 KiB

    const int row0   = blk * ROWS_PER_BLK;
    const int nvalid = min(ROWS_PER_BLK, NROWS - row0);
    const int p      = row0 + tid;           // global row (pair) index in this head

    if (tid < nvalid) {
        // p -> (cell, anchor); cell -> (img, y, x), x fastest.
        const int cell = p / 3;              // magic-mul division
        const int a    = p - cell * 3;
        const int img  = cell / PLANE;
        const int cip  = cell - img * PLANE;
        const int y    = cip / W;
        const int x    = cip - y * W;

        // 5 independent scalar loads, stride PLANE; within a wave each field hits
        // 3 short contiguous segments (one per anchor) -> L1/L2 lines fully reused
        // by neighboring waves of the same block.
        const float* base = in + (size_t)(img * 255 + a * 85) * PLANE + cip;
        const float conf = base[0];
        const float o1   = base[PLANE * 1];
        const float o2   = base[PLANE * 2];
        const float o3   = base[PLANE * 3];
        const float o4   = base[PLANE * 4];

        const bool  m  = conf > thresh;
        const float aw = (a == 0) ? aw0 : ((a == 1) ? aw1 : aw2);
        const float ah = (a == 0) ? ah0 : ((a == 1) ? ah1 : ah2);

        // LDS layout == output order: row-local * 5 + field.
        // Stride 5 words across lanes -> 2-way wave64 bank aliasing only (free).
        float* s = &lds[tid * 5];
        s[0] = m ? (float)img : 0.0f;
        s[1] = m ? ((float)x + o1) * t : 0.0f;
        s[2] = m ? ((float)y + o2) * t : 0.0f;
        s[3] = m ? aw * __expf(o3) : 0.0f;
        s[4] = m ? ah * __expf(o4) : 0.0f;
    }
    __syncthreads();

    // Contiguous float4 flush. nvalid is always divisible by 4 here
    // (tails: 96, 128, full 256) so nvalid*5 is divisible by 4.
    const int nvec = (nvalid * 5) >> 2;      // <= 320 float4
    float4* ov = (float4*)(outf + (size_t)row0 * 5);
    const float4* sv = (const float4*)lds;
    for (int i = tid; i < nvec; i += ROWS_PER_BLK) {
        ov[i] = sv[i];
    }
}

__global__ __launch_bounds__(256) void yolo_decode_all(
    const float* __restrict__ in13,
    const float* __restrict__ in26,
    const float* __restrict__ in52,
    const float* __restrict__ thp,
    float* __restrict__ out) {
    const int tid = threadIdx.x;
    const float thresh = *thp;
    const int blk = blockIdx.x;
    if (blk < BLK13) {
        decode_head_rows<13>(in13, out, blk, tid, thresh,
                             116.0f, 90.0f, 156.0f, 198.0f, 373.0f, 326.0f);
    } else if (blk < BLK13 + BLK26) {
        decode_head_rows<26>(in26, out + (size_t)R13 * 5, blk - BLK13, tid, thresh,
                             30.0f, 61.0f, 62.0f, 45.0f, 59.0f, 119.0f);
    } else {
        decode_head_rows<52>(in52, out + (size_t)(R13 + R26) * 5, blk - (BLK13 + BLK26), tid, thresh,
                             10.0f, 13.0f, 16.0f, 30.0f, 33.0f, 23.0f);
    }
}

extern "C" void kernel_launch(void* const* d_in, const int* in_sizes, int n_in,
                              void* d_out, int out_size, void* d_ws, size_t ws_size,
                              hipStream_t stream) {
    const float* in13 = (const float*)d_in[0];
    const float* in26 = (const float*)d_in[1];
    const float* in52 = (const float*)d_in[2];
    const float* thp  = (const float*)d_in[3];
    float* out = (float*)d_out;

    yolo_decode_all<<<NBLK, 256, 0, stream>>>(in13, in26, in52, thp, out);
}